// Round 2
// baseline (2341.410 us; speedup 1.0000x reference)
//
#include <hip/hip_runtime.h>
#include <hip/hip_cooperative_groups.h>
#include <stdint.h>
#include <stddef.h>

namespace cg = cooperative_groups;

typedef unsigned short u16;
typedef float f32x4 __attribute__((ext_vector_type(4)));
typedef __bf16 bf16x8 __attribute__((ext_vector_type(8)));

#define NNODES 16384
#define HDIM   256
#define MAXD   128
#define BNEPS  1e-5f

__device__ __forceinline__ float bf2f(u16 u) {
  union { uint32_t u; float f; } w; w.u = ((uint32_t)u) << 16; return w.f;
}
__device__ __forceinline__ u16 f2bf(float f) {
  union { float f; uint32_t u; } w; w.f = f;
  return (u16)((w.u + 0x7FFFu + ((w.u >> 16) & 1u)) >> 16);  // RNE
}

union FragB { uint4 q; bf16x8 v; u16 us[8]; };

// BN finalize: fold 8 shadow partials + gamma/beta into scale/shift.
__device__ __forceinline__ void compute_bn(const float* __restrict__ stats,
                                           const float* __restrict__ gamma,
                                           const float* __restrict__ beta,
                                           float* sc_s, float* sh_s, int tid) {
  float s = 0.f, q = 0.f;
#pragma unroll
  for (int i = 0; i < 8; ++i) { s += stats[i * 512 + tid]; q += stats[i * 512 + 256 + tid]; }
  const float inv = 1.f / (float)NNODES;
  float mean = s * inv;
  float var  = q * inv - mean * mean;       // biased variance (jnp.var default)
  float rs = rsqrtf(fmaxf(var, 0.f) + BNEPS);
  float sc = gamma[tid] * rs;
  sc_s[tid] = sc;
  sh_s[tid] = beta[tid] - mean * sc;
}

// ---------------------------------------------------------------------------
// GEMM phase (device fn, fixed grid 512): C[16384][256] = op(A)@W + bias.
// op(A) = relu(A*scale+shift) when BN. Emits col sum/sumsq shadows.
// MFMA 16x16x32_bf16 m97-verified layout: A[m=lane&15][k=quad*8+j],
// B[k=quad*8+j][n=lane&15] (from Wt rows), D row=quad*4+reg, col=lane&15.
// ---------------------------------------------------------------------------
template <int NK, bool BN>
__device__ void gemm_phase(const u16* __restrict__ A, const u16* __restrict__ Wt,
                           const float* __restrict__ bias, const float* __restrict__ statsIn,
                           const float* __restrict__ gamma, const float* __restrict__ beta,
                           u16* __restrict__ C, float* __restrict__ statsOut,
                           float* sc_s, float* sh_s) {
  constexpr int K = NK * 32;
  const int tid = threadIdx.x;
  const int lane = tid & 63;
  const int wave = tid >> 6;
  const int l15 = lane & 15;
  const int quad = lane >> 4;
  const int colbase = wave * 64;

  if constexpr (BN) {
    compute_bn(statsIn, gamma, beta, sc_s, sh_s, tid);
    __syncthreads();
  }

  FragB bfrag[NK][4];
#pragma unroll
  for (int ks = 0; ks < NK; ++ks)
#pragma unroll
    for (int ct = 0; ct < 4; ++ct) {
      int c = colbase + ct * 16 + l15;
      bfrag[ks][ct].q = *(const uint4*)(Wt + (size_t)c * K + ks * 32 + quad * 8);
    }
  float biasv[4];
#pragma unroll
  for (int ct = 0; ct < 4; ++ct) biasv[ct] = bias[colbase + ct * 16 + l15];

  float stS[4] = {0.f, 0.f, 0.f, 0.f};
  float stQ[4] = {0.f, 0.f, 0.f, 0.f};
  const f32x4 z = {0.f, 0.f, 0.f, 0.f};

  for (int rt = blockIdx.x; rt < NNODES / 16; rt += 512) {
    const u16* Arow = A + (size_t)(rt * 16 + l15) * K;
    f32x4 acc[4];
#pragma unroll
    for (int ct = 0; ct < 4; ++ct) acc[ct] = z;
#pragma unroll
    for (int ks = 0; ks < NK; ++ks) {
      FragB af;
      af.q = *(const uint4*)(Arow + ks * 32 + quad * 8);
      if constexpr (BN) {
        int kk = ks * 32 + quad * 8;
#pragma unroll
        for (int e = 0; e < 8; ++e) {
          float av = bf2f(af.us[e]);
          av = fmaxf(av * sc_s[kk + e] + sh_s[kk + e], 0.f);
          af.us[e] = f2bf(av);
        }
      }
#pragma unroll
      for (int ct = 0; ct < 4; ++ct)
        acc[ct] = __builtin_amdgcn_mfma_f32_16x16x32_bf16(af.v, bfrag[ks][ct].v, acc[ct], 0, 0, 0);
    }
#pragma unroll
    for (int ct = 0; ct < 4; ++ct) {
      int c = colbase + ct * 16 + l15;
#pragma unroll
      for (int r = 0; r < 4; ++r) {
        float v = acc[ct][r] + biasv[ct];
        C[(size_t)(rt * 16 + quad * 4 + r) * HDIM + c] = f2bf(v);
        stS[ct] += v;
        stQ[ct] += v * v;
      }
    }
  }
#pragma unroll
  for (int ct = 0; ct < 4; ++ct) {
    float v = stS[ct];
    v += __shfl_xor(v, 16);
    v += __shfl_xor(v, 32);
    float q = stQ[ct];
    q += __shfl_xor(q, 16);
    q += __shfl_xor(q, 32);
    if (quad == 0) {
      int c = colbase + ct * 16 + l15;
      float* dst = statsOut + (size_t)(blockIdx.x & 7) * 512;
      atomicAdd(dst + c, v);
      atomicAdd(dst + 256 + c, q);
    }
  }
}

// ---------------------------------------------------------------------------
// The cooperative mega-kernel: whole pipeline, 1 launch, 7 grid syncs.
// grid MUST be 512 blocks x 256 threads (2 blocks/CU co-resident).
// ---------------------------------------------------------------------------
struct MegaParams {
  const float *x, *adj, *gp;
  const float *w00, *b00, *g00, *be00;
  const float *w01, *b01, *g0,  *be0;
  const float *w10, *b10, *g10, *be10;
  const float *w11, *b11, *g1,  *be1;
  u16 *w00t, *w01t, *w10t, *w11t;
  float* stats; int* cnt; u16* cols; u16* P64; u16* T0; u16* T1;
  float* part; float* out_pool; float* out_nodes;
};

__global__ __launch_bounds__(256, 2) void mega_kernel(MegaParams P) {
  cg::grid_group grid = cg::this_grid();
  const int bid  = blockIdx.x;
  const int t    = threadIdx.x;
  const int wave = t >> 6, lane = t & 63;

  __shared__ __align__(16) char smem[22528];
  float* const sc_s = (float*)smem;           // 1 KB
  float* const sh_s = (float*)(smem + 1024);  // 1 KB
  char*  const aux  = smem + 2048;            // 20.5 KB phase scratch

  // ---- phase 0: zero BN-stat shadows + transpose+bf16 the 4 weights ----
  for (int u = bid; u < 896; u += 512) {
    int b = u;
    if (b < 64)                { P.stats[b * 256 + t] = 0.f; }
    else if ((b -= 64) < 64)   { P.w00t[(size_t)t * 64  + b] = f2bf(P.w00[(size_t)b * 256 + t]); }
    else if ((b -= 64) < 256)  { P.w01t[(size_t)t * 256 + b] = f2bf(P.w01[(size_t)b * 256 + t]); }
    else if ((b -= 256) < 256) { P.w10t[(size_t)t * 256 + b] = f2bf(P.w10[(size_t)b * 256 + t]); }
    else { b -= 256;             P.w11t[(size_t)t * 256 + b] = f2bf(P.w11[(size_t)b * 256 + t]); }
  }

  // ---- phase A: adjacency scan -> CSR lists + pooled1[:,0:64] ----
  {
    float (*red_s)[64] = (float(*)[64])aux;       // 1 KB
    u16* cols_s = (u16*)(aux + 1024);             // 256 B
    int* cnt_s  = (int*)(aux + 1280);
    for (int row = bid; row < NNODES; row += 512) {
      if (t == 0) *cnt_s = 0;
      __syncthreads();
      const float* ar = P.adj + (size_t)row * NNODES;
#pragma unroll
      for (int p = 0; p < 16; ++p) {
        int base = (p * 256 + t) * 4;
        f32x4 v = *(const f32x4*)(ar + base);
        if (v[0] != 0.f || v[1] != 0.f || v[2] != 0.f || v[3] != 0.f) {
#pragma unroll
          for (int q = 0; q < 4; ++q)
            if (v[q] != 0.f) {
              int s = atomicAdd(cnt_s, 1);
              if (s < MAXD) cols_s[s] = (u16)(base + q);
            }
        }
      }
      __syncthreads();
      const int n = min(*cnt_s, MAXD);
      if (t == 0) P.cnt[row] = n;
      if (t < n) P.cols[(size_t)row * MAXD + t] = cols_s[t];
      float acc = 0.f;
      for (int s = wave; s < n; s += 4) acc += P.x[(size_t)cols_s[s] * 64 + lane];
      red_s[wave][lane] = acc;
      __syncthreads();
      if (t < 64)
        P.P64[(size_t)row * 64 + t] = f2bf(red_s[0][t] + red_s[1][t] + red_s[2][t] + red_s[3][t]);
      // next trip's writes to cnt_s/cols_s/red_s are fenced by its leading barrier
    }
  }
  grid.sync();
  // ---- phase B: t1 = pooled1 @ w00 ----
  gemm_phase<2, false>(P.P64, P.w00t, P.b00, nullptr, nullptr, nullptr,
                       P.T0, P.stats + 0, sc_s, sh_s);
  grid.sync();
  // ---- phase C: t2 = relu(bn(t1)) @ w01 ----
  gemm_phase<8, true>(P.T0, P.w01t, P.b01, P.stats + 0, P.g00, P.be00,
                      P.T1, P.stats + 4096, sc_s, sh_s);
  grid.sync();
  // ---- phase D: pooled2 = adj @ relu(bn(t2)) (BN fused into gather) ----
  {
    compute_bn(P.stats + 4096, P.g0, P.be0, sc_s, sh_s, t);
    __syncthreads();
    const float s0 = sc_s[lane * 4],     s1 = sc_s[lane * 4 + 1],
                s2 = sc_s[lane * 4 + 2], s3 = sc_s[lane * 4 + 3];
    const float h0 = sh_s[lane * 4],     h1 = sh_s[lane * 4 + 1],
                h2 = sh_s[lane * 4 + 2], h3 = sh_s[lane * 4 + 3];
    for (int rr = 0; rr < 8; ++rr) {
      const int row = bid * 32 + rr * 4 + wave;
      const int n = P.cnt[row];
      const u16* cl = P.cols + (size_t)row * MAXD;
      float a0 = 0.f, a1 = 0.f, a2 = 0.f, a3 = 0.f;
      for (int s = 0; s < n; ++s) {
        int j = cl[s];
        ushort4 v = *(const ushort4*)(P.T1 + (size_t)j * 256 + lane * 4);
        a0 += fmaxf(bf2f(v.x) * s0 + h0, 0.f);
        a1 += fmaxf(bf2f(v.y) * s1 + h1, 0.f);
        a2 += fmaxf(bf2f(v.z) * s2 + h2, 0.f);
        a3 += fmaxf(bf2f(v.w) * s3 + h3, 0.f);
      }
      ushort4 o;
      o.x = f2bf(a0); o.y = f2bf(a1); o.z = f2bf(a2); o.w = f2bf(a3);
      *(ushort4*)(P.T0 + (size_t)row * 256 + lane * 4) = o;
    }
  }
  grid.sync();
  // ---- phase E: t3 = pooled2 @ w10 ----
  gemm_phase<8, false>(P.T0, P.w10t, P.b10, nullptr, nullptr, nullptr,
                       P.T1, P.stats + 8192, sc_s, sh_s);
  grid.sync();
  // ---- phase F: t4 = relu(bn(t3)) @ w11 ----
  gemm_phase<8, true>(P.T1, P.w11t, P.b11, P.stats + 8192, P.g10, P.be10,
                      P.T0, P.stats + 12288, sc_s, sh_s);
  grid.sync();
  // ---- phase G: h2 = relu(bn(t4)); write h_nodes (gg==0) + pool partials ----
  {
    compute_bn(P.stats + 12288, P.g1, P.be1, sc_s, sh_s, t);
    float (*gpsT)[20] = (float(*)[20])aux;        // 20 KB
    const int gg = bid >> 6, chunk = bid & 63;
#pragma unroll
    for (int g = 0; g < 16; ++g)
      gpsT[t][g] = P.gp[(size_t)(gg * 16 + g) * NNODES + chunk * 256 + t];
    __syncthreads();
    const float scv = sc_s[t], shv = sh_s[t];    // own-thread write, no race
    float acc[16];
#pragma unroll
    for (int g = 0; g < 16; ++g) acc[g] = 0.f;
    const bool wh = (gg == 0);
    for (int j = 0; j < 256; ++j) {
      const int node = chunk * 256 + j;
      float hv = fmaxf(bf2f(P.T0[(size_t)node * 256 + t]) * scv + shv, 0.f);
      if (wh) P.out_nodes[(size_t)node * 256 + t] = hv;
      const float* gb = &gpsT[j][0];
      f32x4 r0 = *(const f32x4*)gb,       r1 = *(const f32x4*)(gb + 4),
            r2 = *(const f32x4*)(gb + 8), r3 = *(const f32x4*)(gb + 12);
#pragma unroll
      for (int g = 0; g < 4; ++g) {
        acc[g]      += r0[g] * hv;
        acc[4 + g]  += r1[g] * hv;
        acc[8 + g]  += r2[g] * hv;
        acc[12 + g] += r3[g] * hv;
      }
    }
#pragma unroll
    for (int g = 0; g < 16; ++g)
      P.part[(size_t)chunk * 32768 + (size_t)(gg * 16 + g) * 256 + t] = acc[g];
  }
  grid.sync();
  // ---- phase H: reduce pool partials ----
  if (bid < 128) {
    float s = 0.f;
#pragma unroll 8
    for (int c = 0; c < 64; ++c) s += P.part[(size_t)c * 32768 + (size_t)bid * 256 + t];
    P.out_pool[(size_t)bid * 256 + t] = s;
  }
}

// ===========================================================================
// Fallback path (round-1 kernel chain) — used only if the cooperative launch
// is rejected (e.g. capture incompatibility).
// ===========================================================================
__global__ void fused_init_csr_kernel(
    const float* __restrict__ w00, const float* __restrict__ w01,
    const float* __restrict__ w10, const float* __restrict__ w11,
    u16* __restrict__ w00t, u16* __restrict__ w01t,
    u16* __restrict__ w10t, u16* __restrict__ w11t,
    float* __restrict__ stats,
    const float* __restrict__ adj, int* __restrict__ cnt, u16* __restrict__ cols,
    const float* __restrict__ x, u16* __restrict__ p64) {
  int b = blockIdx.x, t = threadIdx.x;
  if (b < 896) {
    if (b < 64)  { stats[b * 256 + t] = 0.f; return; }
    b -= 64;
    if (b < 64)  { w00t[(size_t)t * 64  + b] = f2bf(w00[(size_t)b * 256 + t]); return; }
    b -= 64;
    if (b < 256) { w01t[(size_t)t * 256 + b] = f2bf(w01[(size_t)b * 256 + t]); return; }
    b -= 256;
    if (b < 256) { w10t[(size_t)t * 256 + b] = f2bf(w10[(size_t)b * 256 + t]); return; }
    b -= 256;
    w11t[(size_t)t * 256 + b] = f2bf(w11[(size_t)b * 256 + t]);
    return;
  }
  const int row = b - 896;
  __shared__ int cnt_s;
  __shared__ u16 cols_s[MAXD];
  __shared__ __align__(16) float red_s[4][64];
  if (t == 0) cnt_s = 0;
  __syncthreads();
  const float* ar = adj + (size_t)row * NNODES;
#pragma unroll
  for (int p = 0; p < 16; ++p) {
    int base = (p * 256 + t) * 4;
    f32x4 v = *(const f32x4*)(ar + base);
    if (v[0] != 0.f || v[1] != 0.f || v[2] != 0.f || v[3] != 0.f) {
#pragma unroll
      for (int q = 0; q < 4; ++q)
        if (v[q] != 0.f) {
          int s = atomicAdd(&cnt_s, 1);
          if (s < MAXD) cols_s[s] = (u16)(base + q);
        }
    }
  }
  __syncthreads();
  const int n = min(cnt_s, MAXD);
  if (t == 0) cnt[row] = n;
  if (t < n) cols[(size_t)row * MAXD + t] = cols_s[t];
  const int wave = t >> 6, lane = t & 63;
  float acc = 0.f;
  for (int s = wave; s < n; s += 4) acc += x[(size_t)cols_s[s] * 64 + lane];
  red_s[wave][lane] = acc;
  __syncthreads();
  if (t < 64) p64[(size_t)row * 64 + t] = f2bf(red_s[0][t] + red_s[1][t] + red_s[2][t] + red_s[3][t]);
}

__global__ void spmm256_bn_kernel(const int* __restrict__ cnt, const u16* __restrict__ cols,
                                  const u16* __restrict__ T, const float* __restrict__ statsIn,
                                  const float* __restrict__ gamma, const float* __restrict__ beta,
                                  u16* __restrict__ out) {
  __shared__ __align__(16) float sc_s[256];
  __shared__ __align__(16) float sh_s[256];
  const int tid = threadIdx.x;
  compute_bn(statsIn, gamma, beta, sc_s, sh_s, tid);
  __syncthreads();
  const int wave = tid >> 6, lane = tid & 63;
  const int row = blockIdx.x * 4 + wave;
  const int n = cnt[row];
  const u16* cl = cols + (size_t)row * MAXD;
  const float s0 = sc_s[lane * 4], s1 = sc_s[lane * 4 + 1],
              s2 = sc_s[lane * 4 + 2], s3 = sc_s[lane * 4 + 3];
  const float h0 = sh_s[lane * 4], h1 = sh_s[lane * 4 + 1],
              h2 = sh_s[lane * 4 + 2], h3 = sh_s[lane * 4 + 3];
  float a0 = 0.f, a1 = 0.f, a2 = 0.f, a3 = 0.f;
  for (int s = 0; s < n; ++s) {
    int j = cl[s];
    ushort4 v = *(const ushort4*)(T + (size_t)j * 256 + lane * 4);
    a0 += fmaxf(bf2f(v.x) * s0 + h0, 0.f);
    a1 += fmaxf(bf2f(v.y) * s1 + h1, 0.f);
    a2 += fmaxf(bf2f(v.z) * s2 + h2, 0.f);
    a3 += fmaxf(bf2f(v.w) * s3 + h3, 0.f);
  }
  ushort4 o;
  o.x = f2bf(a0); o.y = f2bf(a1); o.z = f2bf(a2); o.w = f2bf(a3);
  *(ushort4*)(out + (size_t)row * 256 + lane * 4) = o;
}

template <int NK, bool BN>
__global__ __launch_bounds__(256, 2) void gemm_kernel(
    const u16* __restrict__ A, const u16* __restrict__ Wt,
    const float* __restrict__ bias, const float* __restrict__ statsIn,
    const float* __restrict__ gamma, const float* __restrict__ beta,
    u16* __restrict__ C, float* __restrict__ statsOut) {
  __shared__ __align__(16) float sc_s[256];
  __shared__ __align__(16) float sh_s[256];
  gemm_phase<NK, BN>(A, Wt, bias, statsIn, gamma, beta, C, statsOut, sc_s, sh_s);
}

template <bool F32OUT>
__global__ void bnrelu_kernel(const u16* __restrict__ T, const float* __restrict__ stats,
                              const float* __restrict__ gamma, const float* __restrict__ beta,
                              u16* __restrict__ out16, float* __restrict__ out32) {
  __shared__ __align__(16) float sc_s[256];
  __shared__ __align__(16) float sh_s[256];
  int tid = threadIdx.x;
  compute_bn(stats, gamma, beta, sc_s, sh_s, tid);
  __syncthreads();
#pragma unroll
  for (int h = 0; h < 2; ++h) {
    size_t idx = (size_t)blockIdx.x * 2048 + h * 1024 + tid * 4;
    ushort4 v = *(const ushort4*)(T + idx);
    int c = (int)(idx & 255);
    float r0 = fmaxf(bf2f(v.x) * sc_s[c]     + sh_s[c],     0.f);
    float r1 = fmaxf(bf2f(v.y) * sc_s[c + 1] + sh_s[c + 1], 0.f);
    float r2 = fmaxf(bf2f(v.z) * sc_s[c + 2] + sh_s[c + 2], 0.f);
    float r3 = fmaxf(bf2f(v.w) * sc_s[c + 3] + sh_s[c + 3], 0.f);
    if constexpr (F32OUT) {
      f32x4 o = {r0, r1, r2, r3};
      *(f32x4*)(out32 + idx) = o;
    } else {
      ushort4 o;
      o.x = f2bf(r0); o.y = f2bf(r1); o.z = f2bf(r2); o.w = f2bf(r3);
      *(ushort4*)(out16 + idx) = o;
    }
  }
}

__global__ void pool_kernel(const float* __restrict__ gp, const float* __restrict__ h2,
                            float* __restrict__ part) {
  int gg = blockIdx.x >> 6, chunk = blockIdx.x & 63;
  int col = threadIdx.x;
  __shared__ __align__(16) float gpsT[256][20];
#pragma unroll
  for (int g = 0; g < 16; ++g)
    gpsT[col][g] = gp[(size_t)(gg * 16 + g) * NNODES + chunk * 256 + col];
  __syncthreads();
  float acc[16];
#pragma unroll
  for (int g = 0; g < 16; ++g) acc[g] = 0.f;
  for (int j = 0; j < 256; ++j) {
    float hv = h2[(size_t)(chunk * 256 + j) * 256 + col];
    const float* gb = &gpsT[j][0];
    f32x4 r0 = *(const f32x4*)(gb);
    f32x4 r1 = *(const f32x4*)(gb + 4);
    f32x4 r2 = *(const f32x4*)(gb + 8);
    f32x4 r3 = *(const f32x4*)(gb + 12);
#pragma unroll
    for (int g = 0; g < 4; ++g) {
      acc[g]      += r0[g] * hv;
      acc[4 + g]  += r1[g] * hv;
      acc[8 + g]  += r2[g] * hv;
      acc[12 + g] += r3[g] * hv;
    }
  }
#pragma unroll
  for (int g = 0; g < 16; ++g)
    part[(size_t)chunk * 32768 + (size_t)(gg * 16 + g) * 256 + col] = acc[g];
}

__global__ void poolfin_kernel(const float* __restrict__ part, float* __restrict__ out0) {
  int g = blockIdx.x, col = threadIdx.x;
  float s = 0.f;
#pragma unroll 8
  for (int c = 0; c < 64; ++c) s += part[(size_t)c * 32768 + (size_t)g * 256 + col];
  out0[(size_t)g * 256 + col] = s;
}

// ---------------------------------------------------------------------------
extern "C" void kernel_launch(void* const* d_in, const int* in_sizes, int n_in,
                              void* d_out, int out_size, void* d_ws, size_t ws_size,
                              hipStream_t stream) {
  (void)in_sizes; (void)n_in; (void)out_size; (void)ws_size;
  const float* x    = (const float*)d_in[0];
  const float* adj  = (const float*)d_in[1];
  const float* gp   = (const float*)d_in[2];
  const float* w00  = (const float*)d_in[3];
  const float* b00  = (const float*)d_in[4];
  const float* g00  = (const float*)d_in[5];
  const float* be00 = (const float*)d_in[6];
  const float* w01  = (const float*)d_in[7];
  const float* b01  = (const float*)d_in[8];
  const float* g0   = (const float*)d_in[9];
  const float* be0  = (const float*)d_in[10];
  const float* w10  = (const float*)d_in[11];
  const float* b10  = (const float*)d_in[12];
  const float* g10  = (const float*)d_in[13];
  const float* be10 = (const float*)d_in[14];
  const float* w11  = (const float*)d_in[15];
  const float* b11  = (const float*)d_in[16];
  const float* g1   = (const float*)d_in[17];
  const float* be1  = (const float*)d_in[18];

  // Workspace map — 22.5 MB total.
  char* ws = (char*)d_ws;
  u16*   colidx = (u16*)(ws + 0);               // 4,194,304  [16384][128] u16
  int*   cnt    = (int*)(ws + 4194304);         //    65,536
  u16*   w00t   = (u16*)(ws + 4259840);         //    32,768  [256][64]
  u16*   w01t   = (u16*)(ws + 4292608);         //   131,072  [256][256]
  u16*   w10t   = (u16*)(ws + 4423680);         //   131,072
  u16*   w11t   = (u16*)(ws + 4554752);         //   131,072
  float* stats  = (float*)(ws + 4685824);       //    65,536  4 bufs x 8 x 512
  u16*   P64    = (u16*)(ws + 4751360);         // 2,097,152  [16384][64] bf16
  u16*   T0     = (u16*)(ws + 6848512);         // 8,388,608  [16384][256] bf16
  u16*   T1     = (u16*)(ws + 15237120);        // 8,388,608  -> ends 23,625,728
  float* part   = (float*)T1;                   // 8 MB fp32, aliases dead t3

  // d_out is FP32 (reference output dtype): pooled [128][256] then h_nodes.
  float* out_pool  = (float*)d_out;
  float* out_nodes = out_pool + 32768;

  MegaParams Pm = { x, adj, gp,
                    w00, b00, g00, be00,
                    w01, b01, g0,  be0,
                    w10, b10, g10, be10,
                    w11, b11, g1,  be1,
                    w00t, w01t, w10t, w11t,
                    stats, cnt, colidx, P64, T0, T1,
                    part, out_pool, out_nodes };
  void* kargs[] = { (void*)&Pm };
  hipError_t e = hipLaunchCooperativeKernel((const void*)mega_kernel,
                                            dim3(512), dim3(256), kargs, 0, stream);
  if (e != hipSuccess) {
    // Fallback: round-1 9-launch chain.
    fused_init_csr_kernel<<<896 + NNODES, 256, 0, stream>>>(
        w00, w01, w10, w11, w00t, w01t, w10t, w11t, stats,
        adj, cnt, colidx, x, P64);
    gemm_kernel<2, false><<<512, 256, 0, stream>>>(P64, w00t, b00, nullptr, nullptr, nullptr,
                                                   T0, stats + 0);
    gemm_kernel<8, true><<<512, 256, 0, stream>>>(T0, w01t, b01, stats + 0, g00, be00,
                                                  T1, stats + 4096);
    spmm256_bn_kernel<<<NNODES / 4, 256, 0, stream>>>(cnt, colidx, T1, stats + 4096, g0, be0,
                                                      T0);
    gemm_kernel<8, false><<<512, 256, 0, stream>>>(T0, w10t, b10, nullptr, nullptr, nullptr,
                                                   T1, stats + 8192);
    gemm_kernel<8, true><<<512, 256, 0, stream>>>(T1, w11t, b11, stats + 8192, g10, be10,
                                                  T0, stats + 12288);
    bnrelu_kernel<true><<<2048, 256, 0, stream>>>(T0, stats + 12288, g1, be1,
                                                  nullptr, out_nodes);
    pool_kernel<<<512, 256, 0, stream>>>(gp, out_nodes, part);
    poolfin_kernel<<<128, 256, 0, stream>>>(part, out_pool);
  }
}

// Round 4
// 1894.911 us; speedup vs baseline: 1.2356x; 1.2356x over previous
//
#include <hip/hip_runtime.h>
#include <hip/hip_cooperative_groups.h>
#include <stdint.h>
#include <stddef.h>

namespace cg = cooperative_groups;

typedef unsigned short u16;
typedef float f32x4 __attribute__((ext_vector_type(4)));
typedef __bf16 bf16x8 __attribute__((ext_vector_type(8)));

#define NNODES 16384
#define HDIM   256
#define MAXD   128
#define BNEPS  1e-5f

__device__ __forceinline__ float bf2f(u16 u) {
  union { uint32_t u; float f; } w; w.u = ((uint32_t)u) << 16; return w.f;
}
__device__ __forceinline__ u16 f2bf(float f) {
  union { float f; uint32_t u; } w; w.f = f;
  return (u16)((w.u + 0x7FFFu + ((w.u >> 16) & 1u)) >> 16);  // RNE
}

union FragB { uint4 q; bf16x8 v; u16 us[8]; };

// BN finalize: fold 8 shadow partials + gamma/beta into scale/shift.
__device__ __forceinline__ void compute_bn(const float* __restrict__ stats,
                                           const float* __restrict__ gamma,
                                           const float* __restrict__ beta,
                                           float* sc_s, float* sh_s, int tid) {
  float s = 0.f, q = 0.f;
#pragma unroll
  for (int i = 0; i < 8; ++i) { s += stats[i * 512 + tid]; q += stats[i * 512 + 256 + tid]; }
  const float inv = 1.f / (float)NNODES;
  float mean = s * inv;
  float var  = q * inv - mean * mean;       // biased variance (jnp.var default)
  float rs = rsqrtf(fmaxf(var, 0.f) + BNEPS);
  float sc = gamma[tid] * rs;
  sc_s[tid] = sc;
  sh_s[tid] = beta[tid] - mean * sc;
}

// ---------------------------------------------------------------------------
// GEMM phase (device fn, 512-block grid-stride): C[16384][256]=op(A)@W+bias.
// op(A) = relu(A*scale+shift) when BN. Emits col sum/sumsq shadows.
// MFMA 16x16x32_bf16 m97-verified layout: A[m=lane&15][k=quad*8+j],
// B[k=quad*8+j][n=lane&15] (from Wt rows), D row=quad*4+reg, col=lane&15.
// ---------------------------------------------------------------------------
template <int NK, bool BN>
__device__ void gemm_phase(const u16* __restrict__ A, const u16* __restrict__ Wt,
                           const float* __restrict__ bias, const float* __restrict__ statsIn,
                           const float* __restrict__ gamma, const float* __restrict__ beta,
                           u16* __restrict__ C, float* __restrict__ statsOut,
                           float* sc_s, float* sh_s) {
  constexpr int K = NK * 32;
  const int tid = threadIdx.x;
  const int lane = tid & 63;
  const int wave = tid >> 6;
  const int l15 = lane & 15;
  const int quad = lane >> 4;
  const int colbase = wave * 64;

  if constexpr (BN) {
    compute_bn(statsIn, gamma, beta, sc_s, sh_s, tid);
    __syncthreads();
  }

  FragB bfrag[NK][4];
#pragma unroll
  for (int ks = 0; ks < NK; ++ks)
#pragma unroll
    for (int ct = 0; ct < 4; ++ct) {
      int c = colbase + ct * 16 + l15;
      bfrag[ks][ct].q = *(const uint4*)(Wt + (size_t)c * K + ks * 32 + quad * 8);
    }
  float biasv[4];
#pragma unroll
  for (int ct = 0; ct < 4; ++ct) biasv[ct] = bias[colbase + ct * 16 + l15];

  float stS[4] = {0.f, 0.f, 0.f, 0.f};
  float stQ[4] = {0.f, 0.f, 0.f, 0.f};
  const f32x4 z = {0.f, 0.f, 0.f, 0.f};

  for (int rt = blockIdx.x; rt < NNODES / 16; rt += 512) {
    const u16* Arow = A + (size_t)(rt * 16 + l15) * K;
    f32x4 acc[4];
#pragma unroll
    for (int ct = 0; ct < 4; ++ct) acc[ct] = z;
#pragma unroll
    for (int ks = 0; ks < NK; ++ks) {
      FragB af;
      af.q = *(const uint4*)(Arow + ks * 32 + quad * 8);
      if constexpr (BN) {
        int kk = ks * 32 + quad * 8;
#pragma unroll
        for (int e = 0; e < 8; ++e) {
          float av = bf2f(af.us[e]);
          av = fmaxf(av * sc_s[kk + e] + sh_s[kk + e], 0.f);
          af.us[e] = f2bf(av);
        }
      }
#pragma unroll
      for (int ct = 0; ct < 4; ++ct)
        acc[ct] = __builtin_amdgcn_mfma_f32_16x16x32_bf16(af.v, bfrag[ks][ct].v, acc[ct], 0, 0, 0);
    }
#pragma unroll
    for (int ct = 0; ct < 4; ++ct) {
      int c = colbase + ct * 16 + l15;
#pragma unroll
      for (int r = 0; r < 4; ++r) {
        float v = acc[ct][r] + biasv[ct];
        C[(size_t)(rt * 16 + quad * 4 + r) * HDIM + c] = f2bf(v);
        stS[ct] += v;
        stQ[ct] += v * v;
      }
    }
  }
#pragma unroll
  for (int ct = 0; ct < 4; ++ct) {
    float v = stS[ct];
    v += __shfl_xor(v, 16);
    v += __shfl_xor(v, 32);
    float q = stQ[ct];
    q += __shfl_xor(q, 16);
    q += __shfl_xor(q, 32);
    if (quad == 0) {
      int c = colbase + ct * 16 + l15;
      float* dst = statsOut + (size_t)(blockIdx.x & 7) * 512;
      atomicAdd(dst + c, v);
      atomicAdd(dst + 256 + c, q);
    }
  }
}

// ---------------------------------------------------------------------------
// K0: init (zero BN shadows, transpose+bf16 weights) + adjacency scan -> CSR
// + pooled1[:,0:64]. Wide launch — latency-bound scan needs block-level
// parallelism (r2 lesson: inside a 512-block coop grid it ran at 11% HBM).
// ---------------------------------------------------------------------------
__global__ void fused_init_csr_kernel(
    const float* __restrict__ w00, const float* __restrict__ w01,
    const float* __restrict__ w10, const float* __restrict__ w11,
    u16* __restrict__ w00t, u16* __restrict__ w01t,
    u16* __restrict__ w10t, u16* __restrict__ w11t,
    float* __restrict__ stats,
    const float* __restrict__ adj, int* __restrict__ cnt, u16* __restrict__ cols,
    const float* __restrict__ x, u16* __restrict__ p64) {
  int b = blockIdx.x, t = threadIdx.x;
  if (b < 896) {
    if (b < 64)  { stats[b * 256 + t] = 0.f; return; }
    b -= 64;
    if (b < 64)  { w00t[(size_t)t * 64  + b] = f2bf(w00[(size_t)b * 256 + t]); return; }
    b -= 64;
    if (b < 256) { w01t[(size_t)t * 256 + b] = f2bf(w01[(size_t)b * 256 + t]); return; }
    b -= 256;
    if (b < 256) { w10t[(size_t)t * 256 + b] = f2bf(w10[(size_t)b * 256 + t]); return; }
    b -= 256;
    w11t[(size_t)t * 256 + b] = f2bf(w11[(size_t)b * 256 + t]);
    return;
  }
  const int row = b - 896;
  __shared__ int cnt_s;
  __shared__ u16 cols_s[MAXD];
  __shared__ __align__(16) float red_s[4][64];
  if (t == 0) cnt_s = 0;
  __syncthreads();
  const float* ar = adj + (size_t)row * NNODES;
#pragma unroll
  for (int p = 0; p < 16; ++p) {
    int base = (p * 256 + t) * 4;
    f32x4 v = *(const f32x4*)(ar + base);
    if (v[0] != 0.f || v[1] != 0.f || v[2] != 0.f || v[3] != 0.f) {
#pragma unroll
      for (int q = 0; q < 4; ++q)
        if (v[q] != 0.f) {
          int s = atomicAdd(&cnt_s, 1);
          if (s < MAXD) cols_s[s] = (u16)(base + q);
        }
    }
  }
  __syncthreads();
  const int n = min(cnt_s, MAXD);
  if (t == 0) cnt[row] = n;
  if (t < n) cols[(size_t)row * MAXD + t] = cols_s[t];
  const int wave = t >> 6, lane = t & 63;
  float acc = 0.f;
  for (int s = wave; s < n; s += 4) acc += x[(size_t)cols_s[s] * 64 + lane];
  red_s[wave][lane] = acc;
  __syncthreads();
  if (t < 64) p64[(size_t)row * 64 + t] = f2bf(red_s[0][t] + red_s[1][t] + red_s[2][t] + red_s[3][t]);
}

// ---------------------------------------------------------------------------
// spmm256+BN: pooled2[i,:] = sum_{j in nbr(i)} relu(bn(t2[j,:])). Wide launch
// (4096 blocks) — latency-bound gather, keep out of the coop grid.
// ---------------------------------------------------------------------------
__global__ void spmm256_bn_kernel(const int* __restrict__ cnt, const u16* __restrict__ cols,
                                  const u16* __restrict__ T, const float* __restrict__ statsIn,
                                  const float* __restrict__ gamma, const float* __restrict__ beta,
                                  u16* __restrict__ out) {
  __shared__ __align__(16) float sc_s[256];
  __shared__ __align__(16) float sh_s[256];
  const int tid = threadIdx.x;
  compute_bn(statsIn, gamma, beta, sc_s, sh_s, tid);
  __syncthreads();
  const int wave = tid >> 6, lane = tid & 63;
  const int row = blockIdx.x * 4 + wave;
  const int n = cnt[row];
  const u16* cl = cols + (size_t)row * MAXD;
  const float s0 = sc_s[lane * 4], s1 = sc_s[lane * 4 + 1],
              s2 = sc_s[lane * 4 + 2], s3 = sc_s[lane * 4 + 3];
  const float h0 = sh_s[lane * 4], h1 = sh_s[lane * 4 + 1],
              h2 = sh_s[lane * 4 + 2], h3 = sh_s[lane * 4 + 3];
  float a0 = 0.f, a1 = 0.f, a2 = 0.f, a3 = 0.f;
  for (int s = 0; s < n; ++s) {
    int j = cl[s];
    ushort4 v = *(const ushort4*)(T + (size_t)j * 256 + lane * 4);
    a0 += fmaxf(bf2f(v.x) * s0 + h0, 0.f);
    a1 += fmaxf(bf2f(v.y) * s1 + h1, 0.f);
    a2 += fmaxf(bf2f(v.z) * s2 + h2, 0.f);
    a3 += fmaxf(bf2f(v.w) * s3 + h3, 0.f);
  }
  ushort4 o;
  o.x = f2bf(a0); o.y = f2bf(a1); o.z = f2bf(a2); o.w = f2bf(a3);
  *(ushort4*)(out + (size_t)row * 256 + lane * 4) = o;
}

// ---------------------------------------------------------------------------
// coopA: gemm1 -> sync -> gemm2.   Grid MUST be 512 (launch_bounds(256,2)
// guarantees exactly 2 blocks/CU co-resident — r2-proven configuration).
// ---------------------------------------------------------------------------
struct CoopAParams {
  const u16* P64; const u16* w00t; const float* b00;
  const u16* w01t; const float* b01; const float* g00; const float* be00;
  u16* T0; u16* T1; float* stats;
};

__global__ __launch_bounds__(256, 2) void coopA_kernel(CoopAParams P) {
  cg::grid_group grid = cg::this_grid();
  __shared__ __align__(16) float sc_s[256];
  __shared__ __align__(16) float sh_s[256];
  gemm_phase<2, false>(P.P64, P.w00t, P.b00, nullptr, nullptr, nullptr,
                       P.T0, P.stats + 0, sc_s, sh_s);
  grid.sync();
  gemm_phase<8, true>(P.T0, P.w01t, P.b01, P.stats + 0, P.g00, P.be00,
                      P.T1, P.stats + 4096, sc_s, sh_s);
}

// ---------------------------------------------------------------------------
// coopB: gemm3 -> sync -> gemm4 -> sync -> bn+h_nodes+pool -> sync -> poolfin.
// Grid 512; phase geometry identical to r2's proven mega phases E..H.
// ---------------------------------------------------------------------------
struct CoopBParams {
  const float* gp;
  const u16* w10t; const float* b10;
  const u16* w11t; const float* b11; const float* g10; const float* be10;
  const float* g1; const float* be1;
  u16* T0; u16* T1; float* stats;
  float* part; float* out_pool; float* out_nodes;
};

__global__ __launch_bounds__(256, 2) void coopB_kernel(CoopBParams P) {
  cg::grid_group grid = cg::this_grid();
  const int bid = blockIdx.x;
  const int t   = threadIdx.x;

  __shared__ __align__(16) char smem[22528];
  float* const sc_s = (float*)smem;           // 1 KB
  float* const sh_s = (float*)(smem + 1024);  // 1 KB
  char*  const aux  = smem + 2048;            // 20 KB phase scratch

  // ---- E: t3 = pooled2 @ w10 ----
  gemm_phase<8, false>(P.T0, P.w10t, P.b10, nullptr, nullptr, nullptr,
                       P.T1, P.stats + 8192, sc_s, sh_s);
  grid.sync();
  // ---- F: t4 = relu(bn(t3)) @ w11 ----
  gemm_phase<8, true>(P.T1, P.w11t, P.b11, P.stats + 8192, P.g10, P.be10,
                      P.T0, P.stats + 12288, sc_s, sh_s);
  grid.sync();
  // ---- G: h2 = relu(bn(t4)); h_nodes (gg==0) + pool partials.
  //         512 blocks: gg = bid>>6 in [0,8), chunk = bid&63 (256 nodes). ----
  {
    compute_bn(P.stats + 12288, P.g1, P.be1, sc_s, sh_s, t);
    float (*gpsT)[20] = (float(*)[20])aux;        // [256][20] = 20 KB
    const int gg = bid >> 6, chunk = bid & 63;
#pragma unroll
    for (int g = 0; g < 16; ++g)
      gpsT[t][g] = P.gp[(size_t)(gg * 16 + g) * NNODES + chunk * 256 + t];
    __syncthreads();
    const float scv = sc_s[t], shv = sh_s[t];    // own-thread BN write, no race
    float acc[16];
#pragma unroll
    for (int g = 0; g < 16; ++g) acc[g] = 0.f;
    const bool wh = (gg == 0);
    for (int j = 0; j < 256; ++j) {
      const int node = chunk * 256 + j;
      float hv = fmaxf(bf2f(P.T0[(size_t)node * 256 + t]) * scv + shv, 0.f);
      if (wh) P.out_nodes[(size_t)node * 256 + t] = hv;
      const float* gb = &gpsT[j][0];
      f32x4 r0 = *(const f32x4*)gb,       r1 = *(const f32x4*)(gb + 4),
            r2 = *(const f32x4*)(gb + 8), r3 = *(const f32x4*)(gb + 12);
#pragma unroll
      for (int g = 0; g < 4; ++g) {
        acc[g]      += r0[g] * hv;
        acc[4 + g]  += r1[g] * hv;
        acc[8 + g]  += r2[g] * hv;
        acc[12 + g] += r3[g] * hv;
      }
    }
#pragma unroll
    for (int g = 0; g < 16; ++g)
      P.part[(size_t)chunk * 32768 + (size_t)(gg * 16 + g) * 256 + t] = acc[g];
  }
  grid.sync();
  // ---- H: reduce pool partials (64 chunks) ----
  if (bid < 128) {
    float s = 0.f;
#pragma unroll 8
    for (int c = 0; c < 64; ++c) s += P.part[(size_t)c * 32768 + (size_t)bid * 256 + t];
    P.out_pool[(size_t)bid * 256 + t] = s;
  }
}

// ===========================================================================
// Fallback standalone kernels (round-1 chain, proven 1551 us).
// ===========================================================================
template <int NK, bool BN>
__global__ __launch_bounds__(256, 2) void gemm_kernel(
    const u16* __restrict__ A, const u16* __restrict__ Wt,
    const float* __restrict__ bias, const float* __restrict__ statsIn,
    const float* __restrict__ gamma, const float* __restrict__ beta,
    u16* __restrict__ C, float* __restrict__ statsOut) {
  __shared__ __align__(16) float sc_s[256];
  __shared__ __align__(16) float sh_s[256];
  gemm_phase<NK, BN>(A, Wt, bias, statsIn, gamma, beta, C, statsOut, sc_s, sh_s);
}

__global__ void bnrelu_f32_kernel(const u16* __restrict__ T, const float* __restrict__ stats,
                                  const float* __restrict__ gamma, const float* __restrict__ beta,
                                  float* __restrict__ out32) {
  __shared__ __align__(16) float sc_s[256];
  __shared__ __align__(16) float sh_s[256];
  int tid = threadIdx.x;
  compute_bn(stats, gamma, beta, sc_s, sh_s, tid);
  __syncthreads();
#pragma unroll
  for (int h = 0; h < 2; ++h) {
    size_t idx = (size_t)blockIdx.x * 2048 + h * 1024 + tid * 4;
    ushort4 v = *(const ushort4*)(T + idx);
    int c = (int)(idx & 255);
    f32x4 o;
    o[0] = fmaxf(bf2f(v.x) * sc_s[c]     + sh_s[c],     0.f);
    o[1] = fmaxf(bf2f(v.y) * sc_s[c + 1] + sh_s[c + 1], 0.f);
    o[2] = fmaxf(bf2f(v.z) * sc_s[c + 2] + sh_s[c + 2], 0.f);
    o[3] = fmaxf(bf2f(v.w) * sc_s[c + 3] + sh_s[c + 3], 0.f);
    *(f32x4*)(out32 + idx) = o;
  }
}

__global__ void pool_kernel(const float* __restrict__ gp, const float* __restrict__ h2,
                            float* __restrict__ part) {
  int gg = blockIdx.x >> 6, chunk = blockIdx.x & 63;
  int col = threadIdx.x;
  __shared__ __align__(16) float gpsT[256][20];
#pragma unroll
  for (int g = 0; g < 16; ++g)
    gpsT[col][g] = gp[(size_t)(gg * 16 + g) * NNODES + chunk * 256 + col];
  __syncthreads();
  float acc[16];
#pragma unroll
  for (int g = 0; g < 16; ++g) acc[g] = 0.f;
  for (int j = 0; j < 256; ++j) {
    float hv = h2[(size_t)(chunk * 256 + j) * 256 + col];
    const float* gb = &gpsT[j][0];
    f32x4 r0 = *(const f32x4*)(gb);
    f32x4 r1 = *(const f32x4*)(gb + 4);
    f32x4 r2 = *(const f32x4*)(gb + 8);
    f32x4 r3 = *(const f32x4*)(gb + 12);
#pragma unroll
    for (int g = 0; g < 4; ++g) {
      acc[g]      += r0[g] * hv;
      acc[4 + g]  += r1[g] * hv;
      acc[8 + g]  += r2[g] * hv;
      acc[12 + g] += r3[g] * hv;
    }
  }
#pragma unroll
  for (int g = 0; g < 16; ++g)
    part[(size_t)chunk * 32768 + (size_t)(gg * 16 + g) * 256 + col] = acc[g];
}

__global__ void poolfin64_kernel(const float* __restrict__ part, float* __restrict__ out0) {
  int g = blockIdx.x, col = threadIdx.x;
  float s = 0.f;
#pragma unroll 8
  for (int c = 0; c < 64; ++c) s += part[(size_t)c * 32768 + (size_t)g * 256 + col];
  out0[(size_t)g * 256 + col] = s;
}

// ---------------------------------------------------------------------------
extern "C" void kernel_launch(void* const* d_in, const int* in_sizes, int n_in,
                              void* d_out, int out_size, void* d_ws, size_t ws_size,
                              hipStream_t stream) {
  (void)in_sizes; (void)n_in; (void)out_size; (void)ws_size;
  const float* x    = (const float*)d_in[0];
  const float* adj  = (const float*)d_in[1];
  const float* gp   = (const float*)d_in[2];
  const float* w00  = (const float*)d_in[3];
  const float* b00  = (const float*)d_in[4];
  const float* g00  = (const float*)d_in[5];
  const float* be00 = (const float*)d_in[6];
  const float* w01  = (const float*)d_in[7];
  const float* b01  = (const float*)d_in[8];
  const float* g0   = (const float*)d_in[9];
  const float* be0  = (const float*)d_in[10];
  const float* w10  = (const float*)d_in[11];
  const float* b10  = (const float*)d_in[12];
  const float* g10  = (const float*)d_in[13];
  const float* be10 = (const float*)d_in[14];
  const float* w11  = (const float*)d_in[15];
  const float* b11  = (const float*)d_in[16];
  const float* g1   = (const float*)d_in[17];
  const float* be1  = (const float*)d_in[18];

  // Workspace map — 23.6 MB total.
  char* ws = (char*)d_ws;
  u16*   colidx = (u16*)(ws + 0);               // 4,194,304  [16384][128] u16
  int*   cnt    = (int*)(ws + 4194304);         //    65,536
  u16*   w00t   = (u16*)(ws + 4259840);         //    32,768  [256][64]
  u16*   w01t   = (u16*)(ws + 4292608);         //   131,072  [256][256]
  u16*   w10t   = (u16*)(ws + 4423680);         //   131,072
  u16*   w11t   = (u16*)(ws + 4554752);         //   131,072
  float* stats  = (float*)(ws + 4685824);       //    65,536  4 bufs x 8 x 512
  u16*   P64    = (u16*)(ws + 4751360);         // 2,097,152  [16384][64] bf16
  u16*   T0     = (u16*)(ws + 6848512);         // 8,388,608  [16384][256] bf16
  u16*   T1     = (u16*)(ws + 15237120);        // 8,388,608  -> ends 23,625,728
  float* part   = (float*)T1;                   // 8 MB fp32, aliases dead t3

  // d_out is FP32 (reference output dtype): pooled [128][256] then h_nodes.
  float* out_pool  = (float*)d_out;
  float* out_nodes = out_pool + 32768;

  // K0: init + adjacency scan (wide — latency-bound).
  fused_init_csr_kernel<<<896 + NNODES, 256, 0, stream>>>(
      w00, w01, w10, w11, w00t, w01t, w10t, w11t, stats,
      adj, cnt, colidx, x, P64);

  // coopA: gemm1 + gemm2 (grid 512, r2-proven coop configuration).
  CoopAParams Pa = { P64, w00t, b00, w01t, b01, g00, be00, T0, T1, stats };
  void* kargsA[] = { (void*)&Pa };
  hipError_t eA = hipLaunchCooperativeKernel((const void*)coopA_kernel,
                                             dim3(512), dim3(256), kargsA, 0, stream);
  if (eA != hipSuccess) {
    gemm_kernel<2, false><<<512, 256, 0, stream>>>(P64, w00t, b00, nullptr, nullptr, nullptr,
                                                   T0, stats + 0);
    gemm_kernel<8, true><<<512, 256, 0, stream>>>(T0, w01t, b01, stats + 0, g00, be00,
                                                  T1, stats + 4096);
  }

  // spmm256+BN (wide — latency-bound gather).
  spmm256_bn_kernel<<<NNODES / 4, 256, 0, stream>>>(cnt, colidx, T1, stats + 4096, g0, be0,
                                                    T0);                     // pooled2 -> T0

  // coopB: gemm3 + gemm4 + bn/h_nodes/pool + poolfin (grid 512).
  CoopBParams Pb = { gp, w10t, b10, w11t, b11, g10, be10, g1, be1,
                     T0, T1, stats, part, out_pool, out_nodes };
  void* kargsB[] = { (void*)&Pb };
  hipError_t eB = hipLaunchCooperativeKernel((const void*)coopB_kernel,
                                             dim3(512), dim3(256), kargsB, 0, stream);
  if (eB != hipSuccess) {
    gemm_kernel<8, false><<<512, 256, 0, stream>>>(T0, w10t, b10, nullptr, nullptr, nullptr,
                                                   T1, stats + 8192);
    gemm_kernel<8, true><<<512, 256, 0, stream>>>(T1, w11t, b11, stats + 8192, g10, be10,
                                                  T0, stats + 12288);
    bnrelu_f32_kernel<<<2048, 256, 0, stream>>>(T0, stats + 12288, g1, be1, out_nodes);
    pool_kernel<<<512, 256, 0, stream>>>(gp, out_nodes, part);
    poolfin64_kernel<<<128, 256, 0, stream>>>(part, out_pool);
  }
}

// Round 6
// 1573.269 us; speedup vs baseline: 1.4882x; 1.2044x over previous
//
#include <hip/hip_runtime.h>
#include <stdint.h>
#include <stddef.h>

typedef unsigned short u16;
typedef float f32x4 __attribute__((ext_vector_type(4)));
typedef __bf16 bf16x8 __attribute__((ext_vector_type(8)));

#define NNODES 16384
#define HDIM   256
#define MAXD   128
#define BNEPS  1e-5f

__device__ __forceinline__ float bf2f(u16 u) {
  union { uint32_t u; float f; } w; w.u = ((uint32_t)u) << 16; return w.f;
}
__device__ __forceinline__ u16 f2bf(float f) {
  union { float f; uint32_t u; } w; w.f = f;
  return (u16)((w.u + 0x7FFFu + ((w.u >> 16) & 1u)) >> 16);  // RNE
}

union FragB { uint4 q; bf16x8 v; u16 us[8]; };

// BN finalize: fold 8 shadow partials + gamma/beta into scale/shift.
__device__ __forceinline__ void compute_bn(const float* __restrict__ stats,
                                           const float* __restrict__ gamma,
                                           const float* __restrict__ beta,
                                           float* sc_s, float* sh_s, int tid) {
  float s = 0.f, q = 0.f;
#pragma unroll
  for (int i = 0; i < 8; ++i) { s += stats[i * 512 + tid]; q += stats[i * 512 + 256 + tid]; }
  const float inv = 1.f / (float)NNODES;
  float mean = s * inv;
  float var  = q * inv - mean * mean;       // biased variance (jnp.var default)
  float rs = rsqrtf(fmaxf(var, 0.f) + BNEPS);
  float sc = gamma[tid] * rs;
  sc_s[tid] = sc;
  sh_s[tid] = beta[tid] - mean * sc;
}

// ---------------------------------------------------------------------------
// K0: init (zero BN shadows + out_pool, transpose+bf16 weights) + adjacency
// scan -> CSR + pooled1[:,0:64]. Wide launch — latency/BW-bound scan needs
// block-level parallelism (r2: inside a 512-block coop grid it ran 11% HBM).
// blocks [0,1024): init; [1024, 1024+16384): one adjacency row each.
// ---------------------------------------------------------------------------
__global__ void fused_init_csr_kernel(
    const float* __restrict__ w00, const float* __restrict__ w01,
    const float* __restrict__ w10, const float* __restrict__ w11,
    u16* __restrict__ w00t, u16* __restrict__ w01t,
    u16* __restrict__ w10t, u16* __restrict__ w11t,
    float* __restrict__ stats, float* __restrict__ out_pool,
    const float* __restrict__ adj, int* __restrict__ cnt, u16* __restrict__ cols,
    const float* __restrict__ x, u16* __restrict__ p64) {
  int b = blockIdx.x, t = threadIdx.x;
  if (b < 1024) {
    if (b < 64)                { stats[b * 256 + t] = 0.f; return; }
    if ((b -= 64) < 64)        { w00t[(size_t)t * 64  + b] = f2bf(w00[(size_t)b * 256 + t]); return; }
    if ((b -= 64) < 256)       { w01t[(size_t)t * 256 + b] = f2bf(w01[(size_t)b * 256 + t]); return; }
    if ((b -= 256) < 256)      { w10t[(size_t)t * 256 + b] = f2bf(w10[(size_t)b * 256 + t]); return; }
    if ((b -= 256) < 256)      { w11t[(size_t)t * 256 + b] = f2bf(w11[(size_t)b * 256 + t]); return; }
    b -= 256;                  // b in [0,128): zero out_pool (atomic target)
    out_pool[(size_t)b * 256 + t] = 0.f;
    return;
  }
  const int row = b - 1024;
  __shared__ int cnt_s;
  __shared__ u16 cols_s[MAXD];
  __shared__ __align__(16) float red_s[4][64];
  if (t == 0) cnt_s = 0;
  __syncthreads();
  const float* ar = adj + (size_t)row * NNODES;
#pragma unroll
  for (int p = 0; p < 16; ++p) {
    int base = (p * 256 + t) * 4;
    f32x4 v = *(const f32x4*)(ar + base);
    if (v[0] != 0.f || v[1] != 0.f || v[2] != 0.f || v[3] != 0.f) {
#pragma unroll
      for (int q = 0; q < 4; ++q)
        if (v[q] != 0.f) {
          int s = atomicAdd(&cnt_s, 1);
          if (s < MAXD) cols_s[s] = (u16)(base + q);
        }
    }
  }
  __syncthreads();
  const int n = min(cnt_s, MAXD);
  if (t == 0) cnt[row] = n;
  if (t < n) cols[(size_t)row * MAXD + t] = cols_s[t];
  const int wave = t >> 6, lane = t & 63;
  float acc = 0.f;
  for (int s = wave; s < n; s += 4) acc += x[(size_t)cols_s[s] * 64 + lane];
  red_s[wave][lane] = acc;
  __syncthreads();
  if (t < 64) p64[(size_t)row * 64 + t] = f2bf(red_s[0][t] + red_s[1][t] + red_s[2][t] + red_s[3][t]);
}

// ---------------------------------------------------------------------------
// MFMA GEMM: C[16384][256] = op(A)[16384][K] @ W[K][256] + bias (bf16 in/out)
//   op(A) = relu(A*scale+shift) when BN. Emits col sum/sumsq shadows (fp32,
//   pre-rounding) for the NEXT BatchNorm.
// MFMA 16x16x32_bf16 m97-verified layout: A[m=lane&15][k=quad*8+j],
// B[k=quad*8+j][n=lane&15] (from Wt rows), D row=quad*4+reg, col=lane&15.
// ---------------------------------------------------------------------------
template <int NK, bool BN>
__global__ __launch_bounds__(256, 2) void gemm_kernel(
    const u16* __restrict__ A, const u16* __restrict__ Wt,
    const float* __restrict__ bias, const float* __restrict__ statsIn,
    const float* __restrict__ gamma, const float* __restrict__ beta,
    u16* __restrict__ C, float* __restrict__ statsOut) {
  constexpr int K = NK * 32;
  const int tid = threadIdx.x;
  const int lane = tid & 63;
  const int wave = tid >> 6;
  const int l15 = lane & 15;
  const int quad = lane >> 4;
  const int colbase = wave * 64;

  __shared__ __align__(16) float sc_s[256];
  __shared__ __align__(16) float sh_s[256];
  if constexpr (BN) {
    compute_bn(statsIn, gamma, beta, sc_s, sh_s, tid);
    __syncthreads();
  }

  FragB bfrag[NK][4];
#pragma unroll
  for (int ks = 0; ks < NK; ++ks)
#pragma unroll
    for (int ct = 0; ct < 4; ++ct) {
      int c = colbase + ct * 16 + l15;
      bfrag[ks][ct].q = *(const uint4*)(Wt + (size_t)c * K + ks * 32 + quad * 8);
    }
  float biasv[4];
#pragma unroll
  for (int ct = 0; ct < 4; ++ct) biasv[ct] = bias[colbase + ct * 16 + l15];

  float stS[4] = {0.f, 0.f, 0.f, 0.f};
  float stQ[4] = {0.f, 0.f, 0.f, 0.f};
  const f32x4 z = {0.f, 0.f, 0.f, 0.f};

  for (int rt = blockIdx.x; rt < NNODES / 16; rt += gridDim.x) {
    const u16* Arow = A + (size_t)(rt * 16 + l15) * K;
    f32x4 acc[4];
#pragma unroll
    for (int ct = 0; ct < 4; ++ct) acc[ct] = z;
#pragma unroll
    for (int ks = 0; ks < NK; ++ks) {
      FragB af;
      af.q = *(const uint4*)(Arow + ks * 32 + quad * 8);
      if constexpr (BN) {
        int kk = ks * 32 + quad * 8;
#pragma unroll
        for (int e = 0; e < 8; ++e) {
          float av = bf2f(af.us[e]);
          av = fmaxf(av * sc_s[kk + e] + sh_s[kk + e], 0.f);
          af.us[e] = f2bf(av);
        }
      }
#pragma unroll
      for (int ct = 0; ct < 4; ++ct)
        acc[ct] = __builtin_amdgcn_mfma_f32_16x16x32_bf16(af.v, bfrag[ks][ct].v, acc[ct], 0, 0, 0);
    }
#pragma unroll
    for (int ct = 0; ct < 4; ++ct) {
      int c = colbase + ct * 16 + l15;
#pragma unroll
      for (int r = 0; r < 4; ++r) {
        float v = acc[ct][r] + biasv[ct];
        C[(size_t)(rt * 16 + quad * 4 + r) * HDIM + c] = f2bf(v);
        stS[ct] += v;
        stQ[ct] += v * v;
      }
    }
  }
#pragma unroll
  for (int ct = 0; ct < 4; ++ct) {
    float v = stS[ct];
    v += __shfl_xor(v, 16);
    v += __shfl_xor(v, 32);
    float q = stQ[ct];
    q += __shfl_xor(q, 16);
    q += __shfl_xor(q, 32);
    if (quad == 0) {
      int c = colbase + ct * 16 + l15;
      float* dst = statsOut + (size_t)(blockIdx.x & 7) * 512;
      atomicAdd(dst + c, v);
      atomicAdd(dst + 256 + c, q);
    }
  }
}

// ---------------------------------------------------------------------------
// spmm256+BN: pooled2[i,:] = sum_{j in nbr(i)} relu(bn(t2[j,:])). Wide launch
// (4096 blocks), 2-way unrolled gather for ILP on the latency-bound loop.
// ---------------------------------------------------------------------------
__global__ void spmm256_bn_kernel(const int* __restrict__ cnt, const u16* __restrict__ cols,
                                  const u16* __restrict__ T, const float* __restrict__ statsIn,
                                  const float* __restrict__ gamma, const float* __restrict__ beta,
                                  u16* __restrict__ out) {
  __shared__ __align__(16) float sc_s[256];
  __shared__ __align__(16) float sh_s[256];
  const int tid = threadIdx.x;
  compute_bn(statsIn, gamma, beta, sc_s, sh_s, tid);
  __syncthreads();
  const int wave = tid >> 6, lane = tid & 63;
  const int row = blockIdx.x * 4 + wave;
  const int n = cnt[row];
  const u16* cl = cols + (size_t)row * MAXD;
  const float s0 = sc_s[lane * 4], s1 = sc_s[lane * 4 + 1],
              s2 = sc_s[lane * 4 + 2], s3 = sc_s[lane * 4 + 3];
  const float h0 = sh_s[lane * 4], h1 = sh_s[lane * 4 + 1],
              h2 = sh_s[lane * 4 + 2], h3 = sh_s[lane * 4 + 3];
  float a0 = 0.f, a1 = 0.f, a2 = 0.f, a3 = 0.f;
  int s = 0;
  for (; s + 2 <= n; s += 2) {
    int j0 = cl[s], j1 = cl[s + 1];
    ushort4 v0 = *(const ushort4*)(T + (size_t)j0 * 256 + lane * 4);
    ushort4 v1 = *(const ushort4*)(T + (size_t)j1 * 256 + lane * 4);
    a0 += fmaxf(bf2f(v0.x) * s0 + h0, 0.f) + fmaxf(bf2f(v1.x) * s0 + h0, 0.f);
    a1 += fmaxf(bf2f(v0.y) * s1 + h1, 0.f) + fmaxf(bf2f(v1.y) * s1 + h1, 0.f);
    a2 += fmaxf(bf2f(v0.z) * s2 + h2, 0.f) + fmaxf(bf2f(v1.z) * s2 + h2, 0.f);
    a3 += fmaxf(bf2f(v0.w) * s3 + h3, 0.f) + fmaxf(bf2f(v1.w) * s3 + h3, 0.f);
  }
  if (s < n) {
    int j = cl[s];
    ushort4 v = *(const ushort4*)(T + (size_t)j * 256 + lane * 4);
    a0 += fmaxf(bf2f(v.x) * s0 + h0, 0.f);
    a1 += fmaxf(bf2f(v.y) * s1 + h1, 0.f);
    a2 += fmaxf(bf2f(v.z) * s2 + h2, 0.f);
    a3 += fmaxf(bf2f(v.w) * s3 + h3, 0.f);
  }
  ushort4 o;
  o.x = f2bf(a0); o.y = f2bf(a1); o.z = f2bf(a2); o.w = f2bf(a3);
  *(ushort4*)(out + (size_t)row * 256 + lane * 4) = o;
}

// ---------------------------------------------------------------------------
// Finale (fuses bnrelu + pool + poolfin): h2 = relu(bn(t4)) from bf16 t4;
// writes h_nodes (gg==0 blocks) and atomically accumulates the graph readout
// into out_pool (zeroed in K0). grid 512 = 8 graph-groups x 64 node-chunks.
// ---------------------------------------------------------------------------
__global__ void finale_kernel(const u16* __restrict__ T, const float* __restrict__ stats,
                              const float* __restrict__ gamma, const float* __restrict__ beta,
                              const float* __restrict__ gp,
                              float* __restrict__ out_pool, float* __restrict__ out_nodes) {
  __shared__ __align__(16) float sc_s[256];
  __shared__ __align__(16) float sh_s[256];
  __shared__ __align__(16) float gpsT[256][20];
  const int t = threadIdx.x;
  const int gg = blockIdx.x >> 6, chunk = blockIdx.x & 63;
  compute_bn(stats, gamma, beta, sc_s, sh_s, t);
#pragma unroll
  for (int g = 0; g < 16; ++g)
    gpsT[t][g] = gp[(size_t)(gg * 16 + g) * NNODES + chunk * 256 + t];
  __syncthreads();
  const float scv = sc_s[t], shv = sh_s[t];
  float acc[16];
#pragma unroll
  for (int g = 0; g < 16; ++g) acc[g] = 0.f;
  const bool wh = (gg == 0);
  for (int j = 0; j < 256; ++j) {
    const int node = chunk * 256 + j;
    float hv = fmaxf(bf2f(T[(size_t)node * 256 + t]) * scv + shv, 0.f);
    if (wh) out_nodes[(size_t)node * 256 + t] = hv;
    const float* gb = &gpsT[j][0];
    f32x4 r0 = *(const f32x4*)gb,       r1 = *(const f32x4*)(gb + 4),
          r2 = *(const f32x4*)(gb + 8), r3 = *(const f32x4*)(gb + 12);
#pragma unroll
    for (int g = 0; g < 4; ++g) {
      acc[g]      += r0[g] * hv;
      acc[4 + g]  += r1[g] * hv;
      acc[8 + g]  += r2[g] * hv;
      acc[12 + g] += r3[g] * hv;
    }
  }
#pragma unroll
  for (int g = 0; g < 16; ++g)
    atomicAdd(out_pool + (size_t)(gg * 16 + g) * 256 + t, acc[g]);
}

// ---------------------------------------------------------------------------
extern "C" void kernel_launch(void* const* d_in, const int* in_sizes, int n_in,
                              void* d_out, int out_size, void* d_ws, size_t ws_size,
                              hipStream_t stream) {
  (void)in_sizes; (void)n_in; (void)out_size; (void)ws_size;
  const float* x    = (const float*)d_in[0];
  const float* adj  = (const float*)d_in[1];
  const float* gp   = (const float*)d_in[2];
  const float* w00  = (const float*)d_in[3];
  const float* b00  = (const float*)d_in[4];
  const float* g00  = (const float*)d_in[5];
  const float* be00 = (const float*)d_in[6];
  const float* w01  = (const float*)d_in[7];
  const float* b01  = (const float*)d_in[8];
  const float* g0   = (const float*)d_in[9];
  const float* be0  = (const float*)d_in[10];
  const float* w10  = (const float*)d_in[11];
  const float* b10  = (const float*)d_in[12];
  const float* g10  = (const float*)d_in[13];
  const float* be10 = (const float*)d_in[14];
  const float* w11  = (const float*)d_in[15];
  const float* b11  = (const float*)d_in[16];
  const float* g1   = (const float*)d_in[17];
  const float* be1  = (const float*)d_in[18];

  // Workspace map — 23.6 MB used.
  char* ws = (char*)d_ws;
  u16*   colidx = (u16*)(ws + 0);               // 4,194,304  [16384][128] u16
  int*   cnt    = (int*)(ws + 4194304);         //    65,536
  u16*   w00t   = (u16*)(ws + 4259840);         //    32,768  [256][64]
  u16*   w01t   = (u16*)(ws + 4292608);         //   131,072  [256][256]
  u16*   w10t   = (u16*)(ws + 4423680);         //   131,072
  u16*   w11t   = (u16*)(ws + 4554752);         //   131,072
  float* stats  = (float*)(ws + 4685824);       //    65,536  4 bufs x 8 x 512
  u16*   P64    = (u16*)(ws + 4751360);         // 2,097,152  [16384][64] bf16
  u16*   T0     = (u16*)(ws + 6848512);         // 8,388,608  [16384][256] bf16
  u16*   T1     = (u16*)(ws + 15237120);        // 8,388,608  -> ends 23,625,728

  // d_out is FP32 (reference output dtype): pooled [128][256] then h_nodes.
  float* out_pool  = (float*)d_out;
  float* out_nodes = out_pool + 32768;

  // K0: init (incl. out_pool zero) + adjacency scan + pooled1.
  fused_init_csr_kernel<<<1024 + NNODES, 256, 0, stream>>>(
      w00, w01, w10, w11, w00t, w01t, w10t, w11t, stats, out_pool,
      adj, cnt, colidx, x, P64);
  // layer 1: t1 = pooled1@w00 ; t2 = relu(bn(t1))@w01
  gemm_kernel<2, false><<<512, 256, 0, stream>>>(P64, w00t, b00, nullptr, nullptr, nullptr,
                                                 T0, stats + 0);
  gemm_kernel<8, true><<<512, 256, 0, stream>>>(T0, w01t, b01, stats + 0, g00, be00,
                                                T1, stats + 4096);
  // layer 2: pooled2 = adj @ relu(bn(t2)) with BN fused into the gather.
  spmm256_bn_kernel<<<NNODES / 4, 256, 0, stream>>>(cnt, colidx, T1, stats + 4096, g0, be0,
                                                    T0);                     // pooled2 -> T0
  gemm_kernel<8, false><<<512, 256, 0, stream>>>(T0, w10t, b10, nullptr, nullptr, nullptr,
                                                 T1, stats + 8192);          // t3 -> T1
  gemm_kernel<8, true><<<512, 256, 0, stream>>>(T1, w11t, b11, stats + 8192, g10, be10,
                                                T0, stats + 12288);          // t4 -> T0
  // finale: h2 = relu(bn(t4)) -> h_nodes + atomic graph readout.
  finale_kernel<<<512, 256, 0, stream>>>(T0, stats + 12288, g1, be1, gp,
                                         out_pool, out_nodes);
}